// Round 9
// baseline (390.744 us; speedup 1.0000x reference)
//
#include <hip/hip_runtime.h>
#include <hip/hip_fp16.h>

#define N_NODES 20000
#define E_EDGES 320000
#define D_DIM   128
#define H1HEADS 4
#define G_GRAPHS 256
#define SLOPE   0.2f

typedef _Float16 h8 __attribute__((ext_vector_type(8)));
typedef float float4v __attribute__((ext_vector_type(4)));

// ---------------- CSR build ----------------
__global__ void cnt_k(const int* __restrict__ dst, int* __restrict__ cnt) {
    int e = blockIdx.x * blockDim.x + threadIdx.x;
    if (e < E_EDGES) atomicAdd(&cnt[dst[e]], 1);
}

// 3-phase multi-block scan (replaces single-block scan_k)
#define SCAN_B 79
__global__ __launch_bounds__(256) void scan1_k(const int* __restrict__ cnt,
                                               int* __restrict__ part) {
    __shared__ int s[256];
    int t = threadIdx.x;
    int i = blockIdx.x * 256 + t;
    int v = (i < N_NODES) ? cnt[i] : 0;
    s[t] = v;
    __syncthreads();
    for (int off = 128; off > 0; off >>= 1) {
        if (t < off) s[t] += s[t + off];
        __syncthreads();
    }
    if (t == 0) part[blockIdx.x] = s[0];
}
__global__ void scan2_k(int* __restrict__ part) {
    if (threadIdx.x == 0) {
        int run = 0;
        for (int b = 0; b < SCAN_B; ++b) { int v = part[b]; part[b] = run; run += v; }
    }
}
__global__ __launch_bounds__(256) void scan3_k(const int* __restrict__ cnt,
                                               const int* __restrict__ part,
                                               int* __restrict__ rowptr) {
    __shared__ int s[256];
    int t = threadIdx.x;
    int i = blockIdx.x * 256 + t;
    int v = (i < N_NODES) ? cnt[i] : 0;
    s[t] = v;
    __syncthreads();
    for (int off = 1; off < 256; off <<= 1) {
        int u = (t >= off) ? s[t - off] : 0;
        __syncthreads();
        s[t] += u;
        __syncthreads();
    }
    if (i < N_NODES) rowptr[i] = part[blockIdx.x] + s[t] - v;   // exclusive
    if (blockIdx.x == 0 && t == 0) rowptr[N_NODES] = E_EDGES;
}

__global__ void scat_k(const int* __restrict__ src, const int* __restrict__ dst,
                       const int* __restrict__ rowptr, int* __restrict__ cur,
                       int* __restrict__ csrsrc) {
    int e = blockIdx.x * blockDim.x + threadIdx.x;
    if (e >= E_EDGES) return;
    int d = dst[e];
    int p = rowptr[d] + atomicAdd(&cur[d], 1);
    csrsrc[p] = src[e];
}

// ---------- 64-lane bitonic sort (ascending) ----------
__device__ __forceinline__ int bitonic64(int key, int lane) {
#pragma unroll
    for (int k = 2; k <= 64; k <<= 1) {
#pragma unroll
        for (int j = k >> 1; j > 0; j >>= 1) {
            int other = __shfl_xor(key, j);
            bool up = ((lane & k) == 0);
            bool lower = ((lane & j) == 0);
            int mn = min(key, other), mx = max(key, other);
            key = (up == lower) ? mn : mx;
        }
    }
    return key;
}

// ---------- canonical per-bucket sort of csrsrc (deg < 64 empirically guaranteed) ----------
__global__ __launch_bounds__(256) void sortb_k(const int* __restrict__ rowptr,
                                               int* __restrict__ csrsrc) {
    const int node = (blockIdx.x * blockDim.x + threadIdx.x) >> 6;
    if (node >= N_NODES) return;
    const int lane = threadIdx.x & 63;
    const int r0 = rowptr[node];
    const int deg = rowptr[node + 1] - r0;
    if (deg <= 1 || deg > 64) return;
    int key = 0x7FFFFFFF;
    if (lane < deg) key = csrsrc[r0 + lane];
    key = bitonic64(key, lane);
    if (lane < deg) csrsrc[r0 + lane] = key;
}

// ---------- weights -> transposed fp16 ----------
__global__ void prepw_k(const float* __restrict__ W1, __half* __restrict__ w1t,
                        const float* __restrict__ W2, __half* __restrict__ w2t) {
    int i = blockIdx.x * blockDim.x + threadIdx.x;
    if (i >= 128 * 512) return;
    {   // W1 [128 x 512] -> T [512 x 128]
        int k = i >> 9, n = i & 511;
        w1t[n * 128 + k] = __float2half(W1[i]);
    }
    {   // W2 [512 x 128] -> T [128 x 512]
        int k = i >> 7, n = i & 127;
        w2t[n * 512 + k] = __float2half(W2[i]);
    }
}

// ---------- MFMA GEMM + fused attention dots ----------
// C[M,N] = A[M,K] * B[K,N]. A fp32, split to fp16 hi/lo in-kernel (exact to 2^-22),
// LDS-staged. B fp16 TRANSPOSED [N x K], direct from global (L2-resident weights).
// 2-pass f16 MFMA, fp32 acc. Tile 64(M) x 128(N), K-chunks of 64.
// Epilogue: als/ald dots from fp32 acc (block owns full head: col0 = by*128, head=by).
__device__ __forceinline__ void store_val(__half* p, float v) { *p = __float2half(v); }
__device__ __forceinline__ void store_val(float* p, float v) { *p = v; }

template <typename OT>
__global__ __launch_bounds__(256) void fgemm_k(const float* __restrict__ A,
                                               const __half* __restrict__ BT,
                                               const int M, const int N, const int K,
                                               OT* __restrict__ C,
                                               float* __restrict__ als,
                                               float* __restrict__ ald,
                                               const float* __restrict__ asrc,
                                               const float* __restrict__ adst) {
    constexpr int SA = 72;   // LDS row stride in halfs
    __shared__ __half Ah[64 * SA], Al[64 * SA];   // 18.4 KB
    __shared__ float sdot[64][2][2];              // 1 KB
    const int t = threadIdx.x;
    const int wave = t >> 6, lane = t & 63;
    const int q = lane >> 4, rr = lane & 15;
    const int row0 = blockIdx.x * 64;
    const int col0 = blockIdx.y * 128;
    const int wm = wave & 1, wn = wave >> 1;
    const int H = gridDim.y;

    float4v acc[2][4];
#pragma unroll
    for (int i = 0; i < 2; ++i)
#pragma unroll
        for (int j = 0; j < 4; ++j) acc[i][j] = (float4v){0.f, 0.f, 0.f, 0.f};

    for (int kc = 0; kc < K; kc += 64) {
        __syncthreads();
        // stage A tile (64 rows x 64 k) fp32 -> hi/lo fp16 in LDS
#pragma unroll
        for (int i = 0; i < 4; ++i) {
            int u = t + i * 256;
            int m = u >> 4, mac = u & 15;       // mac: 16 groups of 4 floats
            int r = row0 + m;
            float4 fv = make_float4(0.f, 0.f, 0.f, 0.f);
            if (r < M) fv = *(const float4*)(A + (size_t)r * K + kc + mac * 4);
            union { __half h[4]; uint2 u2; } ph, pl;
            float f[4] = {fv.x, fv.y, fv.z, fv.w};
#pragma unroll
            for (int k = 0; k < 4; ++k) {
                __half hb = __float2half(f[k]);
                ph.h[k] = hb;
                pl.h[k] = __float2half(f[k] - __half2float(hb));
            }
            *(uint2*)(Ah + m * SA + mac * 4) = ph.u2;
            *(uint2*)(Al + m * SA + mac * 4) = pl.u2;
        }
        __syncthreads();
#pragma unroll
        for (int ks = 0; ks < 2; ++ks) {
            const int ko = ks * 32 + q * 8;
            h8 ah[2], alo[2], bh[4];
#pragma unroll
            for (int mt = 0; mt < 2; ++mt) {
                int m = (wm * 2 + mt) * 16 + rr;
                ah[mt]  = *(const h8*)(Ah + m * SA + ko);
                alo[mt] = *(const h8*)(Al + m * SA + ko);
            }
#pragma unroll
            for (int nt = 0; nt < 4; ++nt) {
                int n = (wn * 4 + nt) * 16 + rr;
                bh[nt] = *(const h8*)(BT + (size_t)(col0 + n) * K + kc + ko);
            }
#pragma unroll
            for (int mt = 0; mt < 2; ++mt)
#pragma unroll
                for (int nt = 0; nt < 4; ++nt) {
                    acc[mt][nt] = __builtin_amdgcn_mfma_f32_16x16x32_f16(
                        ah[mt], bh[nt], acc[mt][nt], 0, 0, 0);
                    acc[mt][nt] = __builtin_amdgcn_mfma_f32_16x16x32_f16(
                        alo[mt], bh[nt], acc[mt][nt], 0, 0, 0);
                }
        }
    }
    // store C (C/D layout: col=lane&15, row=q*4+reg)
#pragma unroll
    for (int mt = 0; mt < 2; ++mt) {
#pragma unroll
        for (int reg = 0; reg < 4; ++reg) {
            int r = row0 + (wm * 2 + mt) * 16 + q * 4 + reg;
            if (r < M) {
#pragma unroll
                for (int nt = 0; nt < 4; ++nt) {
                    int c = col0 + (wn * 4 + nt) * 16 + rr;
                    store_val(&C[(size_t)r * N + c], acc[mt][nt][reg]);
                }
            }
        }
    }
    // fused attention dots: als/ald[r*H + by] = sum_c acc[r][c] * a{src,dst}[by*128 + c]
    ((float*)sdot)[t] = 0.f;
    __syncthreads();
    const float* as = asrc + blockIdx.y * 128;
    const float* ad = adst + blockIdx.y * 128;
#pragma unroll
    for (int mt = 0; mt < 2; ++mt) {
#pragma unroll
        for (int reg = 0; reg < 4; ++reg) {
            float ps = 0.f, pd = 0.f;
#pragma unroll
            for (int nt = 0; nt < 4; ++nt) {
                int cc = (wn * 4 + nt) * 16 + rr;
                float v = acc[mt][nt][reg];
                ps += v * as[cc];
                pd += v * ad[cc];
            }
#pragma unroll
            for (int off = 1; off < 16; off <<= 1) {
                ps += __shfl_xor(ps, off);
                pd += __shfl_xor(pd, off);
            }
            if (rr == 0) {
                int row = (wm * 2 + mt) * 16 + q * 4 + reg;
                sdot[row][wn][0] = ps;
                sdot[row][wn][1] = pd;
            }
        }
    }
    __syncthreads();
    if (t < 64) {
        int r = row0 + t;
        if (r < M) {
            als[r * H + blockIdx.y] = sdot[t][0][0] + sdot[t][1][0];
            ald[r * H + blockIdx.y] = sdot[t][0][1] + sdot[t][1][1];
        }
    }
}

__device__ __forceinline__ float lrelu(float v) { return (v > 0.f) ? v : SLOPE * v; }

// ---------- layer-1 fused softmax + gather-aggregate: ONE WAVE PER NODE (4 heads) ----------
// 4-deep load prefetch in the gather loop; fp32 x1 output.
__global__ __launch_bounds__(256) void agg1_k(const __half* __restrict__ h,
                                              const float4* __restrict__ als4,
                                              const float4* __restrict__ ald4,
                                              const int* __restrict__ rowptr,
                                              const int* __restrict__ csrsrc,
                                              const float* __restrict__ bias,
                                              float* __restrict__ x1) {
    __shared__ int   ss[4][64];
    __shared__ float ws[4][64][4];
    const int node = (blockIdx.x * blockDim.x + threadIdx.x) >> 6;
    if (node >= N_NODES) return;
    const int lane = threadIdx.x & 63;
    const int wv = threadIdx.x >> 6;
    const int head = lane >> 4;
    const int r0 = rowptr[node];
    const int deg = rowptr[node + 1] - r0;
    const int tot = deg + 1;
    const float4 aldn = ald4[node];

    float acc[8] = {};
    float4 d4;

    if (tot <= 64) {
        int s = node;
        if (lane < deg) s = csrsrc[r0 + lane];
        float4 l4 = make_float4(-1e30f, -1e30f, -1e30f, -1e30f);
        if (lane < tot) {
            float4 a = als4[s];
            l4.x = lrelu(a.x + aldn.x); l4.y = lrelu(a.y + aldn.y);
            l4.z = lrelu(a.z + aldn.z); l4.w = lrelu(a.w + aldn.w);
        }
        float4 m4 = l4;
#pragma unroll
        for (int off = 32; off > 0; off >>= 1) {
            m4.x = fmaxf(m4.x, __shfl_xor(m4.x, off));
            m4.y = fmaxf(m4.y, __shfl_xor(m4.y, off));
            m4.z = fmaxf(m4.z, __shfl_xor(m4.z, off));
            m4.w = fmaxf(m4.w, __shfl_xor(m4.w, off));
        }
        float4 w4 = make_float4(0.f, 0.f, 0.f, 0.f);
        if (lane < tot) {
            w4.x = expf(l4.x - m4.x); w4.y = expf(l4.y - m4.y);
            w4.z = expf(l4.z - m4.z); w4.w = expf(l4.w - m4.w);
        }
        d4 = w4;
#pragma unroll
        for (int off = 32; off > 0; off >>= 1) {
            d4.x += __shfl_xor(d4.x, off);
            d4.y += __shfl_xor(d4.y, off);
            d4.z += __shfl_xor(d4.z, off);
            d4.w += __shfl_xor(d4.w, off);
        }
        ss[wv][lane] = s;
        *(float4*)&ws[wv][lane][0] = w4;
        // gather with 4-deep prefetch (all addresses known up front)
        const uint4* hp = (const uint4*)h;   // 64 uint4 per row of 512 halfs
        uint4 buf[4];
#pragma unroll
        for (int i = 0; i < 4; ++i)
            if (i < tot) buf[i] = hp[(size_t)ss[wv][i] * 64 + lane];
        for (int j = 0; j < tot; ++j) {
            uint4 pk = buf[j & 3];
            int jn = j + 4;
            if (jn < tot) buf[j & 3] = hp[(size_t)ss[wv][jn] * 64 + lane];
            float wj = ws[wv][j][head];
            const __half* p = (const __half*)&pk;
#pragma unroll
            for (int k = 0; k < 8; ++k) acc[k] += wj * __half2float(p[k]);
        }
    } else {
        // unreachable in practice (max degree < 64); deterministic since csrsrc sorted
        float4 m4 = make_float4(-1e30f, -1e30f, -1e30f, -1e30f);
        for (int base = 0; base < tot; base += 64) {
            int j = base + lane;
            float4 l4 = make_float4(-1e30f, -1e30f, -1e30f, -1e30f);
            if (j < tot) {
                int s = (j < deg) ? csrsrc[r0 + j] : node;
                float4 a = als4[s];
                l4.x = lrelu(a.x + aldn.x); l4.y = lrelu(a.y + aldn.y);
                l4.z = lrelu(a.z + aldn.z); l4.w = lrelu(a.w + aldn.w);
            }
#pragma unroll
            for (int off = 32; off > 0; off >>= 1) {
                l4.x = fmaxf(l4.x, __shfl_xor(l4.x, off));
                l4.y = fmaxf(l4.y, __shfl_xor(l4.y, off));
                l4.z = fmaxf(l4.z, __shfl_xor(l4.z, off));
                l4.w = fmaxf(l4.w, __shfl_xor(l4.w, off));
            }
            m4.x = fmaxf(m4.x, l4.x); m4.y = fmaxf(m4.y, l4.y);
            m4.z = fmaxf(m4.z, l4.z); m4.w = fmaxf(m4.w, l4.w);
        }
        d4 = make_float4(0.f, 0.f, 0.f, 0.f);
        for (int base = 0; base < tot; base += 64) {
            int j = base + lane;
            int s = node;
            float4 w4 = make_float4(0.f, 0.f, 0.f, 0.f);
            if (j < tot) {
                if (j < deg) s = csrsrc[r0 + j];
                float4 a = als4[s];
                w4.x = expf(lrelu(a.x + aldn.x) - m4.x);
                w4.y = expf(lrelu(a.y + aldn.y) - m4.y);
                w4.z = expf(lrelu(a.z + aldn.z) - m4.z);
                w4.w = expf(lrelu(a.w + aldn.w) - m4.w);
            }
            float4 p4 = w4;
#pragma unroll
            for (int off = 32; off > 0; off >>= 1) {
                p4.x += __shfl_xor(p4.x, off);
                p4.y += __shfl_xor(p4.y, off);
                p4.z += __shfl_xor(p4.z, off);
                p4.w += __shfl_xor(p4.w, off);
            }
            d4.x += p4.x; d4.y += p4.y; d4.z += p4.z; d4.w += p4.w;
            int lim = min(64, tot - base);
            for (int j2 = 0; j2 < lim; ++j2) {
                int sj = __shfl(s, j2);
                float w0 = __shfl(w4.x, j2), w1 = __shfl(w4.y, j2);
                float w2 = __shfl(w4.z, j2), w3 = __shfl(w4.w, j2);
                float wj = (head < 2) ? (head == 0 ? w0 : w1) : (head == 2 ? w2 : w3);
                const uint4 pk = *((const uint4*)(h + (size_t)sj * 512) + lane);
                const __half* p = (const __half*)&pk;
#pragma unroll
                for (int k = 0; k < 8; ++k) acc[k] += wj * __half2float(p[k]);
            }
        }
    }

    const float dsel = (head < 2) ? (head == 0 ? d4.x : d4.y) : (head == 2 ? d4.z : d4.w);
    const float inv = 1.f / dsel;
    const float4 b0 = ((const float4*)bias)[lane * 2];
    const float4 b1 = ((const float4*)bias)[lane * 2 + 1];
    float v[8];
    v[0] = acc[0] * inv + b0.x; v[1] = acc[1] * inv + b0.y;
    v[2] = acc[2] * inv + b0.z; v[3] = acc[3] * inv + b0.w;
    v[4] = acc[4] * inv + b1.x; v[5] = acc[5] * inv + b1.y;
    v[6] = acc[6] * inv + b1.z; v[7] = acc[7] * inv + b1.w;
#pragma unroll
    for (int k = 0; k < 8; ++k) v[k] = (v[k] > 0.f) ? v[k] : expm1f(v[k]);
    float4* orow = (float4*)(x1 + (size_t)node * 512);
    orow[lane * 2]     = make_float4(v[0], v[1], v[2], v[3]);
    orow[lane * 2 + 1] = make_float4(v[4], v[5], v[6], v[7]);
}

// ---------- layer-2 fused agg + relu + graph-max-pool (fp16 features) ----------
__global__ __launch_bounds__(256) void agg2_k(const __half* __restrict__ h,
                                              const float* __restrict__ als,
                                              const float* __restrict__ ald,
                                              const int* __restrict__ rowptr,
                                              const int* __restrict__ csrsrc,
                                              const float* __restrict__ bias,
                                              const int* __restrict__ batch,
                                              int* __restrict__ pooled) {
    __shared__ int   ss[4][64];
    __shared__ float ws[4][64];
    const int node = (blockIdx.x * blockDim.x + threadIdx.x) >> 6;
    if (node >= N_NODES) return;
    const int lane = threadIdx.x & 63;
    const int wv = threadIdx.x >> 6;
    const int r0 = rowptr[node];
    const int deg = rowptr[node + 1] - r0;
    const int tot = deg + 1;
    const float aldn = ald[node];

    float acc0 = 0.f, acc1 = 0.f;
    float denom;

    if (tot <= 64) {
        int s = node;
        if (lane < deg) s = csrsrc[r0 + lane];
        float l = -1e30f, w = 0.f;
        if (lane < tot) l = lrelu(als[s] + aldn);
        float m = l;
#pragma unroll
        for (int off = 32; off > 0; off >>= 1) m = fmaxf(m, __shfl_xor(m, off));
        if (lane < tot) w = expf(l - m);
        denom = w;
#pragma unroll
        for (int off = 32; off > 0; off >>= 1) denom += __shfl_xor(denom, off);
        ss[wv][lane] = s;
        ws[wv][lane] = w;
        const unsigned* hp = (const unsigned*)h;   // 64 half2 per row of 128 halfs
        unsigned buf[4];
#pragma unroll
        for (int i = 0; i < 4; ++i)
            if (i < tot) buf[i] = hp[(size_t)ss[wv][i] * 64 + lane];
        for (int j = 0; j < tot; ++j) {
            unsigned pk = buf[j & 3];
            int jn = j + 4;
            if (jn < tot) buf[j & 3] = hp[(size_t)ss[wv][jn] * 64 + lane];
            float wj = ws[wv][j];
            __half2 hh = *(__half2*)&pk;
            acc0 += wj * __half2float(hh.x);
            acc1 += wj * __half2float(hh.y);
        }
    } else {
        float m = -1e30f;
        for (int base = 0; base < tot; base += 64) {
            int j = base + lane;
            float l = -1e30f;
            if (j < tot) {
                int s = (j < deg) ? csrsrc[r0 + j] : node;
                l = lrelu(als[s] + aldn);
            }
#pragma unroll
            for (int off = 32; off > 0; off >>= 1) l = fmaxf(l, __shfl_xor(l, off));
            m = fmaxf(m, l);
        }
        denom = 0.f;
        for (int base = 0; base < tot; base += 64) {
            int j = base + lane;
            int s = node;
            float w = 0.f;
            if (j < tot) {
                if (j < deg) s = csrsrc[r0 + j];
                w = expf(lrelu(als[s] + aldn) - m);
            }
            float ws2 = w;
#pragma unroll
            for (int off = 32; off > 0; off >>= 1) ws2 += __shfl_xor(ws2, off);
            denom += ws2;
            int lim = min(64, tot - base);
            for (int j2 = 0; j2 < lim; ++j2) {
                int sj = __shfl(s, j2);
                float wj = __shfl(w, j2);
                float2 f = __half22float2(((const __half2*)(h + (size_t)sj * 128))[lane]);
                acc0 += wj * f.x;
                acc1 += wj * f.y;
            }
        }
    }

    const float inv = 1.f / denom;
    float v0 = fmaxf(acc0 * inv + bias[lane * 2], 0.f);
    float v1 = fmaxf(acc1 * inv + bias[lane * 2 + 1], 0.f);
    int* pb = pooled + batch[node] * 128;
    atomicMax(&pb[lane * 2], __float_as_int(v0));
    atomicMax(&pb[lane * 2 + 1], __float_as_int(v1));
}

// ---------- final MLP head: one block per graph ----------
__global__ __launch_bounds__(64) void fc_k(const float* __restrict__ pooled,
                                           const float* __restrict__ w1,
                                           const float* __restrict__ b1,
                                           const float* __restrict__ w2,
                                           const float* __restrict__ b2,
                                           float* __restrict__ out) {
    int g = blockIdx.x;
    __shared__ float p[128];
    int t = threadIdx.x;
    p[t] = pooled[g * 128 + t];
    p[t + 64] = pooled[g * 128 + 64 + t];
    __syncthreads();
    float acc = 0.f;
    if (t < 16) {
        float s = b1[t];
        for (int c = 0; c < 128; ++c) s += p[c] * w1[c * 16 + t];
        s = fmaxf(s, 0.f);
        acc = s * w2[t];
    }
#pragma unroll
    for (int off = 8; off > 0; off >>= 1) acc += __shfl_down(acc, off);
    if (t == 0) out[g] = acc + b2[0];
}

extern "C" void kernel_launch(void* const* d_in, const int* in_sizes, int n_in,
                              void* d_out, int out_size, void* d_ws, size_t ws_size,
                              hipStream_t stream) {
    const float* x      = (const float*)d_in[0];
    const int*   ei     = (const int*)d_in[1];
    const int*   batch  = (const int*)d_in[2];
    const float* W1     = (const float*)d_in[3];
    const float* a_src1 = (const float*)d_in[4];
    const float* a_dst1 = (const float*)d_in[5];
    const float* b1     = (const float*)d_in[6];
    const float* W2     = (const float*)d_in[7];
    const float* a_src2 = (const float*)d_in[8];
    const float* a_dst2 = (const float*)d_in[9];
    const float* b2     = (const float*)d_in[10];
    const float* fc1w   = (const float*)d_in[11];
    const float* fc1b   = (const float*)d_in[12];
    const float* fc2w   = (const float*)d_in[13];
    const float* fc2b   = (const float*)d_in[14];
    float* out = (float*)d_out;

    const int* src = ei;
    const int* dst = ei + E_EDGES;

    // ---- workspace layout (4-byte units) ----
    int*   cnt    = (int*)d_ws;                     // 20,000 (zero region start)
    int*   cur    = cnt + 20000;                    // 20,000
    int*   pooled = cur + 20000;                    // 32,768
    // zero region = 72,768 * 4 = 291,072 bytes
    int*   rowptr = pooled + 32768;                 // 20,004
    int*   part   = rowptr + 20004;                 // 128
    int*   csrsrc = part + 128;                     // 320,000
    __half* h1h   = (__half*)(csrsrc + 320000);     // 10,240,000 halfs
    __half* h2h   = h1h + 10240000;                 //  2,560,000 halfs
    float* als1   = (float*)(h2h + 2560000);        //     80,000
    float* ald1   = als1 + 80000;                   //     80,000
    float* als2   = ald1 + 80000;                   //     20,000
    float* ald2   = als2 + 20000;                   //     20,000
    __half* w1t   = (__half*)(ald2 + 20000);        //     65,536 halfs
    __half* w2t   = w1t + 65536;                    //     65,536 halfs
    float* x1     = (float*)(w2t + 65536);          // 10,240,000 floats

    (void)hipMemsetAsync(d_ws, 0, 72768 * 4, stream);

    // ---- CSR build + canonical sort ----
    cnt_k<<<(E_EDGES + 255) / 256, 256, 0, stream>>>(dst, cnt);
    scan1_k<<<SCAN_B, 256, 0, stream>>>(cnt, part);
    scan2_k<<<1, 64, 0, stream>>>(part);
    scan3_k<<<SCAN_B, 256, 0, stream>>>(cnt, part, rowptr);
    scat_k<<<(E_EDGES + 255) / 256, 256, 0, stream>>>(src, dst, rowptr, cur, csrsrc);
    sortb_k<<<N_NODES / 4, 256, 0, stream>>>(rowptr, csrsrc);

    // ---- weights prep (fp16 transposed) ----
    prepw_k<<<(128 * 512 + 255) / 256, 256, 0, stream>>>(W1, w1t, W2, w2t);

    // ---- layer 1: h1 = x @ W1 + fused attention dots ----
    fgemm_k<__half><<<dim3(313, 4), 256, 0, stream>>>(x, w1t, N_NODES, 512, 128, h1h,
                                                      als1, ald1, a_src1, a_dst1);

    agg1_k<<<N_NODES / 4, 256, 0, stream>>>(h1h, (const float4*)als1, (const float4*)ald1,
                                            rowptr, csrsrc, b1, x1);

    // ---- layer 2: h2 = x1 @ W2 + fused attention dots ----
    fgemm_k<__half><<<dim3(313, 1), 256, 0, stream>>>(x1, w2t, N_NODES, 128, 512, h2h,
                                                      als2, ald2, a_src2, a_dst2);

    agg2_k<<<N_NODES / 4, 256, 0, stream>>>(h2h, als2, ald2, rowptr, csrsrc, b2,
                                            batch, pooled);

    // ---- head ----
    fc_k<<<G_GRAPHS, 64, 0, stream>>>((const float*)pooled, fc1w, fc1b, fc2w, fc2b, out);
}

// Round 10
// 281.825 us; speedup vs baseline: 1.3865x; 1.3865x over previous
//
#include <hip/hip_runtime.h>
#include <hip/hip_fp16.h>

#define N_NODES 20000
#define E_EDGES 320000
#define D_DIM   128
#define H1HEADS 4
#define G_GRAPHS 256
#define SLOPE   0.2f

typedef _Float16 h8 __attribute__((ext_vector_type(8)));
typedef float float4v __attribute__((ext_vector_type(4)));

// ---------------- CSR build ----------------
__global__ void cnt_k(const int* __restrict__ dst, int* __restrict__ cnt) {
    int e = blockIdx.x * blockDim.x + threadIdx.x;
    if (e < E_EDGES) atomicAdd(&cnt[dst[e]], 1);
}

// 3-phase multi-block scan
#define SCAN_B 79
__global__ __launch_bounds__(256) void scan1_k(const int* __restrict__ cnt,
                                               int* __restrict__ part) {
    __shared__ int s[256];
    int t = threadIdx.x;
    int i = blockIdx.x * 256 + t;
    int v = (i < N_NODES) ? cnt[i] : 0;
    s[t] = v;
    __syncthreads();
    for (int off = 128; off > 0; off >>= 1) {
        if (t < off) s[t] += s[t + off];
        __syncthreads();
    }
    if (t == 0) part[blockIdx.x] = s[0];
}
__global__ void scan2_k(int* __restrict__ part) {
    if (threadIdx.x == 0) {
        int run = 0;
        for (int b = 0; b < SCAN_B; ++b) { int v = part[b]; part[b] = run; run += v; }
    }
}
__global__ __launch_bounds__(256) void scan3_k(const int* __restrict__ cnt,
                                               const int* __restrict__ part,
                                               int* __restrict__ rowptr) {
    __shared__ int s[256];
    int t = threadIdx.x;
    int i = blockIdx.x * 256 + t;
    int v = (i < N_NODES) ? cnt[i] : 0;
    s[t] = v;
    __syncthreads();
    for (int off = 1; off < 256; off <<= 1) {
        int u = (t >= off) ? s[t - off] : 0;
        __syncthreads();
        s[t] += u;
        __syncthreads();
    }
    if (i < N_NODES) rowptr[i] = part[blockIdx.x] + s[t] - v;   // exclusive
    if (blockIdx.x == 0 && t == 0) rowptr[N_NODES] = E_EDGES;
}

__global__ void scat_k(const int* __restrict__ src, const int* __restrict__ dst,
                       const int* __restrict__ rowptr, int* __restrict__ cur,
                       int* __restrict__ csrsrc) {
    int e = blockIdx.x * blockDim.x + threadIdx.x;
    if (e >= E_EDGES) return;
    int d = dst[e];
    int p = rowptr[d] + atomicAdd(&cur[d], 1);
    csrsrc[p] = src[e];
}

// ---------- 64-lane bitonic sort (ascending) ----------
__device__ __forceinline__ int bitonic64(int key, int lane) {
#pragma unroll
    for (int k = 2; k <= 64; k <<= 1) {
#pragma unroll
        for (int j = k >> 1; j > 0; j >>= 1) {
            int other = __shfl_xor(key, j);
            bool up = ((lane & k) == 0);
            bool lower = ((lane & j) == 0);
            int mn = min(key, other), mx = max(key, other);
            key = (up == lower) ? mn : mx;
        }
    }
    return key;
}

// ---------- canonical per-bucket sort of csrsrc (deg < 64 empirically guaranteed) ----------
__global__ __launch_bounds__(256) void sortb_k(const int* __restrict__ rowptr,
                                               int* __restrict__ csrsrc) {
    const int node = (blockIdx.x * blockDim.x + threadIdx.x) >> 6;
    if (node >= N_NODES) return;
    const int lane = threadIdx.x & 63;
    const int r0 = rowptr[node];
    const int deg = rowptr[node + 1] - r0;
    if (deg <= 1 || deg > 64) return;
    int key = 0x7FFFFFFF;
    if (lane < deg) key = csrsrc[r0 + lane];
    key = bitonic64(key, lane);
    if (lane < deg) csrsrc[r0 + lane] = key;
}

// ---------- weights -> transposed fp16 ----------
__global__ void prepw_k(const float* __restrict__ W1, __half* __restrict__ w1t,
                        const float* __restrict__ W2, __half* __restrict__ w2t) {
    int i = blockIdx.x * blockDim.x + threadIdx.x;
    if (i >= 128 * 512) return;
    {   // W1 [128 x 512] -> T [512 x 128]
        int k = i >> 9, n = i & 511;
        w1t[n * 128 + k] = __float2half(W1[i]);
    }
    {   // W2 [512 x 128] -> T [128 x 512]
        int k = i >> 7, n = i & 127;
        w2t[n * 512 + k] = __float2half(W2[i]);
    }
}

// ---------- MFMA GEMM + fused attention dots ----------
// C[M,N] = A[M,K] * B[K,N]. A fp32, split to fp16 hi/lo in-kernel (exact to 2^-22),
// LDS-staged. B fp16 TRANSPOSED [N x K], direct from global (L2-resident weights).
// 2-pass f16 MFMA, fp32 acc. Tile 64(M) x 128(N), K-chunks of 64.
// Epilogue: als/ald dots from fp32 acc (block owns full head: col0 = by*128, head=by).
__device__ __forceinline__ void store_val(__half* p, float v) { *p = __float2half(v); }
__device__ __forceinline__ void store_val(float* p, float v) { *p = v; }

template <typename OT>
__global__ __launch_bounds__(256) void fgemm_k(const float* __restrict__ A,
                                               const __half* __restrict__ BT,
                                               const int M, const int N, const int K,
                                               OT* __restrict__ C,
                                               float* __restrict__ als,
                                               float* __restrict__ ald,
                                               const float* __restrict__ asrc,
                                               const float* __restrict__ adst) {
    constexpr int SA = 72;   // LDS row stride in halfs
    __shared__ __half Ah[64 * SA], Al[64 * SA];   // 18.4 KB
    __shared__ float sdot[64][2][2];              // 1 KB
    const int t = threadIdx.x;
    const int wave = t >> 6, lane = t & 63;
    const int q = lane >> 4, rr = lane & 15;
    const int row0 = blockIdx.x * 64;
    const int col0 = blockIdx.y * 128;
    const int wm = wave & 1, wn = wave >> 1;
    const int H = gridDim.y;

    float4v acc[2][4];
#pragma unroll
    for (int i = 0; i < 2; ++i)
#pragma unroll
        for (int j = 0; j < 4; ++j) acc[i][j] = (float4v){0.f, 0.f, 0.f, 0.f};

    for (int kc = 0; kc < K; kc += 64) {
        __syncthreads();
        // stage A tile (64 rows x 64 k) fp32 -> hi/lo fp16 in LDS
#pragma unroll
        for (int i = 0; i < 4; ++i) {
            int u = t + i * 256;
            int m = u >> 4, mac = u & 15;       // mac: 16 groups of 4 floats
            int r = row0 + m;
            float4 fv = make_float4(0.f, 0.f, 0.f, 0.f);
            if (r < M) fv = *(const float4*)(A + (size_t)r * K + kc + mac * 4);
            union { __half h[4]; uint2 u2; } ph, pl;
            float f[4] = {fv.x, fv.y, fv.z, fv.w};
#pragma unroll
            for (int k = 0; k < 4; ++k) {
                __half hb = __float2half(f[k]);
                ph.h[k] = hb;
                pl.h[k] = __float2half(f[k] - __half2float(hb));
            }
            *(uint2*)(Ah + m * SA + mac * 4) = ph.u2;
            *(uint2*)(Al + m * SA + mac * 4) = pl.u2;
        }
        __syncthreads();
#pragma unroll
        for (int ks = 0; ks < 2; ++ks) {
            const int ko = ks * 32 + q * 8;
            h8 ah[2], alo[2], bh[4];
#pragma unroll
            for (int mt = 0; mt < 2; ++mt) {
                int m = (wm * 2 + mt) * 16 + rr;
                ah[mt]  = *(const h8*)(Ah + m * SA + ko);
                alo[mt] = *(const h8*)(Al + m * SA + ko);
            }
#pragma unroll
            for (int nt = 0; nt < 4; ++nt) {
                int n = (wn * 4 + nt) * 16 + rr;
                bh[nt] = *(const h8*)(BT + (size_t)(col0 + n) * K + kc + ko);
            }
#pragma unroll
            for (int mt = 0; mt < 2; ++mt)
#pragma unroll
                for (int nt = 0; nt < 4; ++nt) {
                    acc[mt][nt] = __builtin_amdgcn_mfma_f32_16x16x32_f16(
                        ah[mt], bh[nt], acc[mt][nt], 0, 0, 0);
                    acc[mt][nt] = __builtin_amdgcn_mfma_f32_16x16x32_f16(
                        alo[mt], bh[nt], acc[mt][nt], 0, 0, 0);
                }
        }
    }
    // store C (C/D layout: col=lane&15, row=q*4+reg)
#pragma unroll
    for (int mt = 0; mt < 2; ++mt) {
#pragma unroll
        for (int reg = 0; reg < 4; ++reg) {
            int r = row0 + (wm * 2 + mt) * 16 + q * 4 + reg;
            if (r < M) {
#pragma unroll
                for (int nt = 0; nt < 4; ++nt) {
                    int c = col0 + (wn * 4 + nt) * 16 + rr;
                    store_val(&C[(size_t)r * N + c], acc[mt][nt][reg]);
                }
            }
        }
    }
    // fused attention dots: als/ald[r*H + by] = sum_c acc[r][c] * a{src,dst}[by*128 + c]
    ((float*)sdot)[t] = 0.f;
    __syncthreads();
    const float* as = asrc + blockIdx.y * 128;
    const float* ad = adst + blockIdx.y * 128;
#pragma unroll
    for (int mt = 0; mt < 2; ++mt) {
#pragma unroll
        for (int reg = 0; reg < 4; ++reg) {
            float ps = 0.f, pd = 0.f;
#pragma unroll
            for (int nt = 0; nt < 4; ++nt) {
                int cc = (wn * 4 + nt) * 16 + rr;
                float v = acc[mt][nt][reg];
                ps += v * as[cc];
                pd += v * ad[cc];
            }
#pragma unroll
            for (int off = 1; off < 16; off <<= 1) {
                ps += __shfl_xor(ps, off);
                pd += __shfl_xor(pd, off);
            }
            if (rr == 0) {
                int row = (wm * 2 + mt) * 16 + q * 4 + reg;
                sdot[row][wn][0] = ps;
                sdot[row][wn][1] = pd;
            }
        }
    }
    __syncthreads();
    if (t < 64) {
        int r = row0 + t;
        if (r < M) {
            als[r * H + blockIdx.y] = sdot[t][0][0] + sdot[t][1][0];
            ald[r * H + blockIdx.y] = sdot[t][0][1] + sdot[t][1][1];
        }
    }
}

__device__ __forceinline__ float lrelu(float v) { return (v > 0.f) ? v : SLOPE * v; }

// ---------- layer-1 fused softmax + gather-aggregate: ONE WAVE PER NODE (4 heads) ----------
// Gather loop 4-wide manually unrolled (independent named loads -> MLP, no reg-array).
__global__ __launch_bounds__(256) void agg1_k(const __half* __restrict__ h,
                                              const float4* __restrict__ als4,
                                              const float4* __restrict__ ald4,
                                              const int* __restrict__ rowptr,
                                              const int* __restrict__ csrsrc,
                                              const float* __restrict__ bias,
                                              float* __restrict__ x1) {
    __shared__ int   ss[4][64];
    __shared__ float ws[4][64][4];
    const int node = (blockIdx.x * blockDim.x + threadIdx.x) >> 6;
    if (node >= N_NODES) return;
    const int lane = threadIdx.x & 63;
    const int wv = threadIdx.x >> 6;
    const int head = lane >> 4;
    const int r0 = rowptr[node];
    const int deg = rowptr[node + 1] - r0;
    const int tot = deg + 1;
    const float4 aldn = ald4[node];

    float acc[8] = {};
    float4 d4;

    if (tot <= 64) {
        int s = node;
        if (lane < deg) s = csrsrc[r0 + lane];
        float4 l4 = make_float4(-1e30f, -1e30f, -1e30f, -1e30f);
        if (lane < tot) {
            float4 a = als4[s];
            l4.x = lrelu(a.x + aldn.x); l4.y = lrelu(a.y + aldn.y);
            l4.z = lrelu(a.z + aldn.z); l4.w = lrelu(a.w + aldn.w);
        }
        float4 m4 = l4;
#pragma unroll
        for (int off = 32; off > 0; off >>= 1) {
            m4.x = fmaxf(m4.x, __shfl_xor(m4.x, off));
            m4.y = fmaxf(m4.y, __shfl_xor(m4.y, off));
            m4.z = fmaxf(m4.z, __shfl_xor(m4.z, off));
            m4.w = fmaxf(m4.w, __shfl_xor(m4.w, off));
        }
        float4 w4 = make_float4(0.f, 0.f, 0.f, 0.f);
        if (lane < tot) {
            w4.x = expf(l4.x - m4.x); w4.y = expf(l4.y - m4.y);
            w4.z = expf(l4.z - m4.z); w4.w = expf(l4.w - m4.w);
        }
        d4 = w4;
#pragma unroll
        for (int off = 32; off > 0; off >>= 1) {
            d4.x += __shfl_xor(d4.x, off);
            d4.y += __shfl_xor(d4.y, off);
            d4.z += __shfl_xor(d4.z, off);
            d4.w += __shfl_xor(d4.w, off);
        }
        ss[wv][lane] = s;
        *(float4*)&ws[wv][lane][0] = w4;
        const uint4* hp = (const uint4*)h;   // 64 uint4 per row of 512 halfs
        int j = 0;
        for (; j + 4 <= tot; j += 4) {
            // four independent loads, issued together
            uint4 pk0 = hp[(size_t)ss[wv][j]     * 64 + lane];
            uint4 pk1 = hp[(size_t)ss[wv][j + 1] * 64 + lane];
            uint4 pk2 = hp[(size_t)ss[wv][j + 2] * 64 + lane];
            uint4 pk3 = hp[(size_t)ss[wv][j + 3] * 64 + lane];
            float wj0 = ws[wv][j][head],     wj1 = ws[wv][j + 1][head];
            float wj2 = ws[wv][j + 2][head], wj3 = ws[wv][j + 3][head];
            const __half* p0 = (const __half*)&pk0;
            const __half* p1 = (const __half*)&pk1;
            const __half* p2 = (const __half*)&pk2;
            const __half* p3 = (const __half*)&pk3;
#pragma unroll
            for (int k = 0; k < 8; ++k) acc[k] += wj0 * __half2float(p0[k]);
#pragma unroll
            for (int k = 0; k < 8; ++k) acc[k] += wj1 * __half2float(p1[k]);
#pragma unroll
            for (int k = 0; k < 8; ++k) acc[k] += wj2 * __half2float(p2[k]);
#pragma unroll
            for (int k = 0; k < 8; ++k) acc[k] += wj3 * __half2float(p3[k]);
        }
        for (; j < tot; ++j) {
            uint4 pk = hp[(size_t)ss[wv][j] * 64 + lane];
            float wj = ws[wv][j][head];
            const __half* p = (const __half*)&pk;
#pragma unroll
            for (int k = 0; k < 8; ++k) acc[k] += wj * __half2float(p[k]);
        }
    } else {
        // unreachable in practice (max degree < 64); deterministic since csrsrc sorted
        float4 m4 = make_float4(-1e30f, -1e30f, -1e30f, -1e30f);
        for (int base = 0; base < tot; base += 64) {
            int j = base + lane;
            float4 l4 = make_float4(-1e30f, -1e30f, -1e30f, -1e30f);
            if (j < tot) {
                int s = (j < deg) ? csrsrc[r0 + j] : node;
                float4 a = als4[s];
                l4.x = lrelu(a.x + aldn.x); l4.y = lrelu(a.y + aldn.y);
                l4.z = lrelu(a.z + aldn.z); l4.w = lrelu(a.w + aldn.w);
            }
#pragma unroll
            for (int off = 32; off > 0; off >>= 1) {
                l4.x = fmaxf(l4.x, __shfl_xor(l4.x, off));
                l4.y = fmaxf(l4.y, __shfl_xor(l4.y, off));
                l4.z = fmaxf(l4.z, __shfl_xor(l4.z, off));
                l4.w = fmaxf(l4.w, __shfl_xor(l4.w, off));
            }
            m4.x = fmaxf(m4.x, l4.x); m4.y = fmaxf(m4.y, l4.y);
            m4.z = fmaxf(m4.z, l4.z); m4.w = fmaxf(m4.w, l4.w);
        }
        d4 = make_float4(0.f, 0.f, 0.f, 0.f);
        for (int base = 0; base < tot; base += 64) {
            int j = base + lane;
            int s = node;
            float4 w4 = make_float4(0.f, 0.f, 0.f, 0.f);
            if (j < tot) {
                if (j < deg) s = csrsrc[r0 + j];
                float4 a = als4[s];
                w4.x = expf(lrelu(a.x + aldn.x) - m4.x);
                w4.y = expf(lrelu(a.y + aldn.y) - m4.y);
                w4.z = expf(lrelu(a.z + aldn.z) - m4.z);
                w4.w = expf(lrelu(a.w + aldn.w) - m4.w);
            }
            float4 p4 = w4;
#pragma unroll
            for (int off = 32; off > 0; off >>= 1) {
                p4.x += __shfl_xor(p4.x, off);
                p4.y += __shfl_xor(p4.y, off);
                p4.z += __shfl_xor(p4.z, off);
                p4.w += __shfl_xor(p4.w, off);
            }
            d4.x += p4.x; d4.y += p4.y; d4.z += p4.z; d4.w += p4.w;
            int lim = min(64, tot - base);
            for (int j2 = 0; j2 < lim; ++j2) {
                int sj = __shfl(s, j2);
                float w0 = __shfl(w4.x, j2), w1 = __shfl(w4.y, j2);
                float w2 = __shfl(w4.z, j2), w3 = __shfl(w4.w, j2);
                float wj = (head < 2) ? (head == 0 ? w0 : w1) : (head == 2 ? w2 : w3);
                const uint4 pk = *((const uint4*)(h + (size_t)sj * 512) + lane);
                const __half* p = (const __half*)&pk;
#pragma unroll
                for (int k = 0; k < 8; ++k) acc[k] += wj * __half2float(p[k]);
            }
        }
    }

    const float dsel = (head < 2) ? (head == 0 ? d4.x : d4.y) : (head == 2 ? d4.z : d4.w);
    const float inv = 1.f / dsel;
    const float4 b0 = ((const float4*)bias)[lane * 2];
    const float4 b1 = ((const float4*)bias)[lane * 2 + 1];
    float v[8];
    v[0] = acc[0] * inv + b0.x; v[1] = acc[1] * inv + b0.y;
    v[2] = acc[2] * inv + b0.z; v[3] = acc[3] * inv + b0.w;
    v[4] = acc[4] * inv + b1.x; v[5] = acc[5] * inv + b1.y;
    v[6] = acc[6] * inv + b1.z; v[7] = acc[7] * inv + b1.w;
#pragma unroll
    for (int k = 0; k < 8; ++k) v[k] = (v[k] > 0.f) ? v[k] : expm1f(v[k]);
    float4* orow = (float4*)(x1 + (size_t)node * 512);
    orow[lane * 2]     = make_float4(v[0], v[1], v[2], v[3]);
    orow[lane * 2 + 1] = make_float4(v[4], v[5], v[6], v[7]);
}

// ---------- layer-2 fused agg + relu + graph-max-pool (fp16 features) ----------
__global__ __launch_bounds__(256) void agg2_k(const __half* __restrict__ h,
                                              const float* __restrict__ als,
                                              const float* __restrict__ ald,
                                              const int* __restrict__ rowptr,
                                              const int* __restrict__ csrsrc,
                                              const float* __restrict__ bias,
                                              const int* __restrict__ batch,
                                              int* __restrict__ pooled) {
    __shared__ int   ss[4][64];
    __shared__ float ws[4][64];
    const int node = (blockIdx.x * blockDim.x + threadIdx.x) >> 6;
    if (node >= N_NODES) return;
    const int lane = threadIdx.x & 63;
    const int wv = threadIdx.x >> 6;
    const int r0 = rowptr[node];
    const int deg = rowptr[node + 1] - r0;
    const int tot = deg + 1;
    const float aldn = ald[node];

    float acc0 = 0.f, acc1 = 0.f;
    float denom;

    if (tot <= 64) {
        int s = node;
        if (lane < deg) s = csrsrc[r0 + lane];
        float l = -1e30f, w = 0.f;
        if (lane < tot) l = lrelu(als[s] + aldn);
        float m = l;
#pragma unroll
        for (int off = 32; off > 0; off >>= 1) m = fmaxf(m, __shfl_xor(m, off));
        if (lane < tot) w = expf(l - m);
        denom = w;
#pragma unroll
        for (int off = 32; off > 0; off >>= 1) denom += __shfl_xor(denom, off);
        ss[wv][lane] = s;
        ws[wv][lane] = w;
        const unsigned* hp = (const unsigned*)h;   // 64 half2 per row of 128 halfs
        int j = 0;
        for (; j + 4 <= tot; j += 4) {
            unsigned pk0 = hp[(size_t)ss[wv][j]     * 64 + lane];
            unsigned pk1 = hp[(size_t)ss[wv][j + 1] * 64 + lane];
            unsigned pk2 = hp[(size_t)ss[wv][j + 2] * 64 + lane];
            unsigned pk3 = hp[(size_t)ss[wv][j + 3] * 64 + lane];
            float wj0 = ws[wv][j], wj1 = ws[wv][j + 1];
            float wj2 = ws[wv][j + 2], wj3 = ws[wv][j + 3];
            float2 f0 = __half22float2(*(__half2*)&pk0);
            float2 f1 = __half22float2(*(__half2*)&pk1);
            float2 f2 = __half22float2(*(__half2*)&pk2);
            float2 f3 = __half22float2(*(__half2*)&pk3);
            acc0 += wj0 * f0.x; acc1 += wj0 * f0.y;
            acc0 += wj1 * f1.x; acc1 += wj1 * f1.y;
            acc0 += wj2 * f2.x; acc1 += wj2 * f2.y;
            acc0 += wj3 * f3.x; acc1 += wj3 * f3.y;
        }
        for (; j < tot; ++j) {
            unsigned pk = hp[(size_t)ss[wv][j] * 64 + lane];
            float wj = ws[wv][j];
            float2 f = __half22float2(*(__half2*)&pk);
            acc0 += wj * f.x;
            acc1 += wj * f.y;
        }
    } else {
        float m = -1e30f;
        for (int base = 0; base < tot; base += 64) {
            int j = base + lane;
            float l = -1e30f;
            if (j < tot) {
                int s = (j < deg) ? csrsrc[r0 + j] : node;
                l = lrelu(als[s] + aldn);
            }
#pragma unroll
            for (int off = 32; off > 0; off >>= 1) l = fmaxf(l, __shfl_xor(l, off));
            m = fmaxf(m, l);
        }
        denom = 0.f;
        for (int base = 0; base < tot; base += 64) {
            int j = base + lane;
            int s = node;
            float w = 0.f;
            if (j < tot) {
                if (j < deg) s = csrsrc[r0 + j];
                w = expf(lrelu(als[s] + aldn) - m);
            }
            float ws2 = w;
#pragma unroll
            for (int off = 32; off > 0; off >>= 1) ws2 += __shfl_xor(ws2, off);
            denom += ws2;
            int lim = min(64, tot - base);
            for (int j2 = 0; j2 < lim; ++j2) {
                int sj = __shfl(s, j2);
                float wj = __shfl(w, j2);
                float2 f = __half22float2(((const __half2*)(h + (size_t)sj * 128))[lane]);
                acc0 += wj * f.x;
                acc1 += wj * f.y;
            }
        }
    }

    const float inv = 1.f / denom;
    float v0 = fmaxf(acc0 * inv + bias[lane * 2], 0.f);
    float v1 = fmaxf(acc1 * inv + bias[lane * 2 + 1], 0.f);
    int* pb = pooled + batch[node] * 128;
    atomicMax(&pb[lane * 2], __float_as_int(v0));
    atomicMax(&pb[lane * 2 + 1], __float_as_int(v1));
}

// ---------- final MLP head: one block per graph ----------
__global__ __launch_bounds__(64) void fc_k(const float* __restrict__ pooled,
                                           const float* __restrict__ w1,
                                           const float* __restrict__ b1,
                                           const float* __restrict__ w2,
                                           const float* __restrict__ b2,
                                           float* __restrict__ out) {
    int g = blockIdx.x;
    __shared__ float p[128];
    int t = threadIdx.x;
    p[t] = pooled[g * 128 + t];
    p[t + 64] = pooled[g * 128 + 64 + t];
    __syncthreads();
    float acc = 0.f;
    if (t < 16) {
        float s = b1[t];
        for (int c = 0; c < 128; ++c) s += p[c] * w1[c * 16 + t];
        s = fmaxf(s, 0.f);
        acc = s * w2[t];
    }
#pragma unroll
    for (int off = 8; off > 0; off >>= 1) acc += __shfl_down(acc, off);
    if (t == 0) out[g] = acc + b2[0];
}

extern "C" void kernel_launch(void* const* d_in, const int* in_sizes, int n_in,
                              void* d_out, int out_size, void* d_ws, size_t ws_size,
                              hipStream_t stream) {
    const float* x      = (const float*)d_in[0];
    const int*   ei     = (const int*)d_in[1];
    const int*   batch  = (const int*)d_in[2];
    const float* W1     = (const float*)d_in[3];
    const float* a_src1 = (const float*)d_in[4];
    const float* a_dst1 = (const float*)d_in[5];
    const float* b1     = (const float*)d_in[6];
    const float* W2     = (const float*)d_in[7];
    const float* a_src2 = (const float*)d_in[8];
    const float* a_dst2 = (const float*)d_in[9];
    const float* b2     = (const float*)d_in[10];
    const float* fc1w   = (const float*)d_in[11];
    const float* fc1b   = (const float*)d_in[12];
    const float* fc2w   = (const float*)d_in[13];
    const float* fc2b   = (const float*)d_in[14];
    float* out = (float*)d_out;

    const int* src = ei;
    const int* dst = ei + E_EDGES;

    // ---- workspace layout (4-byte units) ----
    int*   cnt    = (int*)d_ws;                     // 20,000 (zero region start)
    int*   cur    = cnt + 20000;                    // 20,000
    int*   pooled = cur + 20000;                    // 32,768
    // zero region = 72,768 * 4 = 291,072 bytes
    int*   rowptr = pooled + 32768;                 // 20,004
    int*   part   = rowptr + 20004;                 // 128
    int*   csrsrc = part + 128;                     // 320,000
    __half* h1h   = (__half*)(csrsrc + 320000);     // 10,240,000 halfs
    __half* h2h   = h1h + 10240000;                 //  2,560,000 halfs
    float* als1   = (float*)(h2h + 2560000);        //     80,000
    float* ald1   = als1 + 80000;                   //     80,000
    float* als2   = ald1 + 80000;                   //     20,000
    float* ald2   = als2 + 20000;                   //     20,000
    __half* w1t   = (__half*)(ald2 + 20000);        //     65,536 halfs
    __half* w2t   = w1t + 65536;                    //     65,536 halfs
    float* x1     = (float*)(w2t + 65536);          // 10,240,000 floats

    (void)hipMemsetAsync(d_ws, 0, 72768 * 4, stream);

    // ---- CSR build + canonical sort ----
    cnt_k<<<(E_EDGES + 255) / 256, 256, 0, stream>>>(dst, cnt);
    scan1_k<<<SCAN_B, 256, 0, stream>>>(cnt, part);
    scan2_k<<<1, 64, 0, stream>>>(part);
    scan3_k<<<SCAN_B, 256, 0, stream>>>(cnt, part, rowptr);
    scat_k<<<(E_EDGES + 255) / 256, 256, 0, stream>>>(src, dst, rowptr, cur, csrsrc);
    sortb_k<<<N_NODES / 4, 256, 0, stream>>>(rowptr, csrsrc);

    // ---- weights prep (fp16 transposed) ----
    prepw_k<<<(128 * 512 + 255) / 256, 256, 0, stream>>>(W1, w1t, W2, w2t);

    // ---- layer 1: h1 = x @ W1 + fused attention dots ----
    fgemm_k<__half><<<dim3(313, 4), 256, 0, stream>>>(x, w1t, N_NODES, 512, 128, h1h,
                                                      als1, ald1, a_src1, a_dst1);

    agg1_k<<<N_NODES / 4, 256, 0, stream>>>(h1h, (const float4*)als1, (const float4*)ald1,
                                            rowptr, csrsrc, b1, x1);

    // ---- layer 2: h2 = x1 @ W2 + fused attention dots ----
    fgemm_k<__half><<<dim3(313, 1), 256, 0, stream>>>(x1, w2t, N_NODES, 128, 512, h2h,
                                                      als2, ald2, a_src2, a_dst2);

    agg2_k<<<N_NODES / 4, 256, 0, stream>>>(h2h, als2, ald2, rowptr, csrsrc, b2,
                                            batch, pooled);

    // ---- head ----
    fc_k<<<G_GRAPHS, 64, 0, stream>>>((const float*)pooled, fc1w, fc1b, fc2w, fc2b, out);
}

// Round 11
// 275.530 us; speedup vs baseline: 1.4182x; 1.0228x over previous
//
#include <hip/hip_runtime.h>
#include <hip/hip_fp16.h>

#define N_NODES 20000
#define E_EDGES 320000
#define D_DIM   128
#define H1HEADS 4
#define G_GRAPHS 256
#define SLOPE   0.2f

typedef _Float16 h8 __attribute__((ext_vector_type(8)));
typedef float float4v __attribute__((ext_vector_type(4)));

// ---------------- CSR build (+ fused weight prep) ----------------
__global__ void cntprep_k(const int* __restrict__ dst, int* __restrict__ cnt,
                          const float* __restrict__ W1, __half* __restrict__ w1t,
                          const float* __restrict__ W2, __half* __restrict__ w2t) {
    int i = blockIdx.x * blockDim.x + threadIdx.x;
    if (i < E_EDGES) atomicAdd(&cnt[dst[i]], 1);
    if (i < 128 * 512) {
        {   // W1 [128 x 512] -> T [512 x 128]
            int k = i >> 9, n = i & 511;
            w1t[n * 128 + k] = __float2half(W1[i]);
        }
        {   // W2 [512 x 128] -> T [128 x 512]
            int k = i >> 7, n = i & 127;
            w2t[n * 512 + k] = __float2half(W2[i]);
        }
    }
}

// 3-phase multi-block scan
#define SCAN_B 79
__global__ __launch_bounds__(256) void scan1_k(const int* __restrict__ cnt,
                                               int* __restrict__ part) {
    __shared__ int s[256];
    int t = threadIdx.x;
    int i = blockIdx.x * 256 + t;
    int v = (i < N_NODES) ? cnt[i] : 0;
    s[t] = v;
    __syncthreads();
    for (int off = 128; off > 0; off >>= 1) {
        if (t < off) s[t] += s[t + off];
        __syncthreads();
    }
    if (t == 0) part[blockIdx.x] = s[0];
}
__global__ __launch_bounds__(128) void scan2_k(int* __restrict__ part) {
    __shared__ int s[128];
    int t = threadIdx.x;
    int v = (t < SCAN_B) ? part[t] : 0;
    s[t] = v;
    __syncthreads();
    for (int off = 1; off < 128; off <<= 1) {
        int u = (t >= off) ? s[t - off] : 0;
        __syncthreads();
        s[t] += u;
        __syncthreads();
    }
    if (t < SCAN_B) part[t] = s[t] - v;   // exclusive
}
__global__ __launch_bounds__(256) void scan3_k(const int* __restrict__ cnt,
                                               const int* __restrict__ part,
                                               int* __restrict__ rowptr) {
    __shared__ int s[256];
    int t = threadIdx.x;
    int i = blockIdx.x * 256 + t;
    int v = (i < N_NODES) ? cnt[i] : 0;
    s[t] = v;
    __syncthreads();
    for (int off = 1; off < 256; off <<= 1) {
        int u = (t >= off) ? s[t - off] : 0;
        __syncthreads();
        s[t] += u;
        __syncthreads();
    }
    if (i < N_NODES) rowptr[i] = part[blockIdx.x] + s[t] - v;   // exclusive
    if (blockIdx.x == 0 && t == 0) rowptr[N_NODES] = E_EDGES;
}

__global__ void scat_k(const int* __restrict__ src, const int* __restrict__ dst,
                       const int* __restrict__ rowptr, int* __restrict__ cur,
                       int* __restrict__ csrsrc) {
    int e = blockIdx.x * blockDim.x + threadIdx.x;
    if (e >= E_EDGES) return;
    int d = dst[e];
    int p = rowptr[d] + atomicAdd(&cur[d], 1);
    csrsrc[p] = src[e];
}

// ---------- 64-lane bitonic sort (ascending) ----------
__device__ __forceinline__ int bitonic64(int key, int lane) {
#pragma unroll
    for (int k = 2; k <= 64; k <<= 1) {
#pragma unroll
        for (int j = k >> 1; j > 0; j >>= 1) {
            int other = __shfl_xor(key, j);
            bool up = ((lane & k) == 0);
            bool lower = ((lane & j) == 0);
            int mn = min(key, other), mx = max(key, other);
            key = (up == lower) ? mn : mx;
        }
    }
    return key;
}

// ---------- canonical per-bucket sort of csrsrc (deg < 64 empirically guaranteed) ----------
__global__ __launch_bounds__(256) void sortb_k(const int* __restrict__ rowptr,
                                               int* __restrict__ csrsrc) {
    const int node = (blockIdx.x * blockDim.x + threadIdx.x) >> 6;
    if (node >= N_NODES) return;
    const int lane = threadIdx.x & 63;
    const int r0 = rowptr[node];
    const int deg = rowptr[node + 1] - r0;
    if (deg <= 1 || deg > 64) return;
    int key = 0x7FFFFFFF;
    if (lane < deg) key = csrsrc[r0 + lane];
    key = bitonic64(key, lane);
    if (lane < deg) csrsrc[r0 + lane] = key;
}

// ---------- MFMA GEMM + fused attention dots ----------
// C[M,N] = A[M,K] * B[K,N]. A fp32, split to fp16 hi/lo in-kernel (exact to 2^-22),
// LDS-staged. B fp16 TRANSPOSED [N x K], direct from global (L2-resident weights).
// 2-pass f16 MFMA, fp32 acc. Tile 64(M) x 128(N), K-chunks of 64.
// Epilogue: als/ald dots from fp32 acc (block owns full head: col0 = by*128, head=by).
__device__ __forceinline__ void store_val(__half* p, float v) { *p = __float2half(v); }
__device__ __forceinline__ void store_val(float* p, float v) { *p = v; }

template <typename OT>
__global__ __launch_bounds__(256) void fgemm_k(const float* __restrict__ A,
                                               const __half* __restrict__ BT,
                                               const int M, const int N, const int K,
                                               OT* __restrict__ C,
                                               float* __restrict__ als,
                                               float* __restrict__ ald,
                                               const float* __restrict__ asrc,
                                               const float* __restrict__ adst) {
    constexpr int SA = 72;   // LDS row stride in halfs
    __shared__ __half Ah[64 * SA], Al[64 * SA];   // 18.4 KB
    __shared__ float sdot[64][2][2];              // 1 KB
    const int t = threadIdx.x;
    const int wave = t >> 6, lane = t & 63;
    const int q = lane >> 4, rr = lane & 15;
    const int row0 = blockIdx.x * 64;
    const int col0 = blockIdx.y * 128;
    const int wm = wave & 1, wn = wave >> 1;
    const int H = gridDim.y;

    float4v acc[2][4];
#pragma unroll
    for (int i = 0; i < 2; ++i)
#pragma unroll
        for (int j = 0; j < 4; ++j) acc[i][j] = (float4v){0.f, 0.f, 0.f, 0.f};

    for (int kc = 0; kc < K; kc += 64) {
        __syncthreads();
        // stage A tile (64 rows x 64 k) fp32 -> hi/lo fp16 in LDS
#pragma unroll
        for (int i = 0; i < 4; ++i) {
            int u = t + i * 256;
            int m = u >> 4, mac = u & 15;       // mac: 16 groups of 4 floats
            int r = row0 + m;
            float4 fv = make_float4(0.f, 0.f, 0.f, 0.f);
            if (r < M) fv = *(const float4*)(A + (size_t)r * K + kc + mac * 4);
            union { __half h[4]; uint2 u2; } ph, pl;
            float f[4] = {fv.x, fv.y, fv.z, fv.w};
#pragma unroll
            for (int k = 0; k < 4; ++k) {
                __half hb = __float2half(f[k]);
                ph.h[k] = hb;
                pl.h[k] = __float2half(f[k] - __half2float(hb));
            }
            *(uint2*)(Ah + m * SA + mac * 4) = ph.u2;
            *(uint2*)(Al + m * SA + mac * 4) = pl.u2;
        }
        __syncthreads();
#pragma unroll
        for (int ks = 0; ks < 2; ++ks) {
            const int ko = ks * 32 + q * 8;
            h8 ah[2], alo[2], bh[4];
#pragma unroll
            for (int mt = 0; mt < 2; ++mt) {
                int m = (wm * 2 + mt) * 16 + rr;
                ah[mt]  = *(const h8*)(Ah + m * SA + ko);
                alo[mt] = *(const h8*)(Al + m * SA + ko);
            }
#pragma unroll
            for (int nt = 0; nt < 4; ++nt) {
                int n = (wn * 4 + nt) * 16 + rr;
                bh[nt] = *(const h8*)(BT + (size_t)(col0 + n) * K + kc + ko);
            }
#pragma unroll
            for (int mt = 0; mt < 2; ++mt)
#pragma unroll
                for (int nt = 0; nt < 4; ++nt) {
                    acc[mt][nt] = __builtin_amdgcn_mfma_f32_16x16x32_f16(
                        ah[mt], bh[nt], acc[mt][nt], 0, 0, 0);
                    acc[mt][nt] = __builtin_amdgcn_mfma_f32_16x16x32_f16(
                        alo[mt], bh[nt], acc[mt][nt], 0, 0, 0);
                }
        }
    }
    // store C (C/D layout: col=lane&15, row=q*4+reg)
#pragma unroll
    for (int mt = 0; mt < 2; ++mt) {
#pragma unroll
        for (int reg = 0; reg < 4; ++reg) {
            int r = row0 + (wm * 2 + mt) * 16 + q * 4 + reg;
            if (r < M) {
#pragma unroll
                for (int nt = 0; nt < 4; ++nt) {
                    int c = col0 + (wn * 4 + nt) * 16 + rr;
                    store_val(&C[(size_t)r * N + c], acc[mt][nt][reg]);
                }
            }
        }
    }
    // fused attention dots: als/ald[r*H + by] = sum_c acc[r][c] * a{src,dst}[by*128 + c]
    ((float*)sdot)[t] = 0.f;
    __syncthreads();
    const float* as = asrc + blockIdx.y * 128;
    const float* ad = adst + blockIdx.y * 128;
#pragma unroll
    for (int mt = 0; mt < 2; ++mt) {
#pragma unroll
        for (int reg = 0; reg < 4; ++reg) {
            float ps = 0.f, pd = 0.f;
#pragma unroll
            for (int nt = 0; nt < 4; ++nt) {
                int cc = (wn * 4 + nt) * 16 + rr;
                float v = acc[mt][nt][reg];
                ps += v * as[cc];
                pd += v * ad[cc];
            }
#pragma unroll
            for (int off = 1; off < 16; off <<= 1) {
                ps += __shfl_xor(ps, off);
                pd += __shfl_xor(pd, off);
            }
            if (rr == 0) {
                int row = (wm * 2 + mt) * 16 + q * 4 + reg;
                sdot[row][wn][0] = ps;
                sdot[row][wn][1] = pd;
            }
        }
    }
    __syncthreads();
    if (t < 64) {
        int r = row0 + t;
        if (r < M) {
            als[r * H + blockIdx.y] = sdot[t][0][0] + sdot[t][1][0];
            ald[r * H + blockIdx.y] = sdot[t][0][1] + sdot[t][1][1];
        }
    }
}

__device__ __forceinline__ float lrelu(float v) { return (v > 0.f) ? v : SLOPE * v; }

// ---------- layer-1 fused softmax + gather-aggregate: ONE NODE PER 64-THREAD BLOCK ----------
// Wave-granular scheduling (no intra-block tail imbalance); 8-wide unrolled gather.
__global__ __launch_bounds__(64) void agg1_k(const __half* __restrict__ h,
                                             const float4* __restrict__ als4,
                                             const float4* __restrict__ ald4,
                                             const int* __restrict__ rowptr,
                                             const int* __restrict__ csrsrc,
                                             const float* __restrict__ bias,
                                             float* __restrict__ x1) {
    __shared__ int   ss[64];
    __shared__ float ws[64][4];
    const int node = blockIdx.x;
    const int lane = threadIdx.x;
    const int head = lane >> 4;
    const int r0 = rowptr[node];
    const int deg = rowptr[node + 1] - r0;
    const int tot = deg + 1;
    const float4 aldn = ald4[node];

    float acc[8] = {};
    float4 d4;

    if (tot <= 64) {
        int s = node;
        if (lane < deg) s = csrsrc[r0 + lane];
        float4 l4 = make_float4(-1e30f, -1e30f, -1e30f, -1e30f);
        if (lane < tot) {
            float4 a = als4[s];
            l4.x = lrelu(a.x + aldn.x); l4.y = lrelu(a.y + aldn.y);
            l4.z = lrelu(a.z + aldn.z); l4.w = lrelu(a.w + aldn.w);
        }
        float4 m4 = l4;
#pragma unroll
        for (int off = 32; off > 0; off >>= 1) {
            m4.x = fmaxf(m4.x, __shfl_xor(m4.x, off));
            m4.y = fmaxf(m4.y, __shfl_xor(m4.y, off));
            m4.z = fmaxf(m4.z, __shfl_xor(m4.z, off));
            m4.w = fmaxf(m4.w, __shfl_xor(m4.w, off));
        }
        float4 w4 = make_float4(0.f, 0.f, 0.f, 0.f);
        if (lane < tot) {
            w4.x = expf(l4.x - m4.x); w4.y = expf(l4.y - m4.y);
            w4.z = expf(l4.z - m4.z); w4.w = expf(l4.w - m4.w);
        }
        d4 = w4;
#pragma unroll
        for (int off = 32; off > 0; off >>= 1) {
            d4.x += __shfl_xor(d4.x, off);
            d4.y += __shfl_xor(d4.y, off);
            d4.z += __shfl_xor(d4.z, off);
            d4.w += __shfl_xor(d4.w, off);
        }
        ss[lane] = s;
        *(float4*)&ws[lane][0] = w4;    // same-wave LDS, no barrier needed
        const uint4* hp = (const uint4*)h;   // 64 uint4 per row of 512 halfs
        int j = 0;
        for (; j + 8 <= tot; j += 8) {
            uint4 k0 = hp[(size_t)ss[j]     * 64 + lane];
            uint4 k1 = hp[(size_t)ss[j + 1] * 64 + lane];
            uint4 k2 = hp[(size_t)ss[j + 2] * 64 + lane];
            uint4 k3 = hp[(size_t)ss[j + 3] * 64 + lane];
            uint4 k4 = hp[(size_t)ss[j + 4] * 64 + lane];
            uint4 k5 = hp[(size_t)ss[j + 5] * 64 + lane];
            uint4 k6 = hp[(size_t)ss[j + 6] * 64 + lane];
            uint4 k7 = hp[(size_t)ss[j + 7] * 64 + lane];
            float w0 = ws[j][head],     w1 = ws[j + 1][head];
            float w2 = ws[j + 2][head], w3 = ws[j + 3][head];
            float w4s = ws[j + 4][head], w5 = ws[j + 5][head];
            float w6 = ws[j + 6][head], w7 = ws[j + 7][head];
            const __half *p0 = (const __half*)&k0, *p1 = (const __half*)&k1;
            const __half *p2 = (const __half*)&k2, *p3 = (const __half*)&k3;
            const __half *p4 = (const __half*)&k4, *p5 = (const __half*)&k5;
            const __half *p6 = (const __half*)&k6, *p7 = (const __half*)&k7;
#pragma unroll
            for (int k = 0; k < 8; ++k) acc[k] += w0 * __half2float(p0[k]);
#pragma unroll
            for (int k = 0; k < 8; ++k) acc[k] += w1 * __half2float(p1[k]);
#pragma unroll
            for (int k = 0; k < 8; ++k) acc[k] += w2 * __half2float(p2[k]);
#pragma unroll
            for (int k = 0; k < 8; ++k) acc[k] += w3 * __half2float(p3[k]);
#pragma unroll
            for (int k = 0; k < 8; ++k) acc[k] += w4s * __half2float(p4[k]);
#pragma unroll
            for (int k = 0; k < 8; ++k) acc[k] += w5 * __half2float(p5[k]);
#pragma unroll
            for (int k = 0; k < 8; ++k) acc[k] += w6 * __half2float(p6[k]);
#pragma unroll
            for (int k = 0; k < 8; ++k) acc[k] += w7 * __half2float(p7[k]);
        }
        for (; j + 4 <= tot; j += 4) {
            uint4 k0 = hp[(size_t)ss[j]     * 64 + lane];
            uint4 k1 = hp[(size_t)ss[j + 1] * 64 + lane];
            uint4 k2 = hp[(size_t)ss[j + 2] * 64 + lane];
            uint4 k3 = hp[(size_t)ss[j + 3] * 64 + lane];
            float w0 = ws[j][head],     w1 = ws[j + 1][head];
            float w2 = ws[j + 2][head], w3 = ws[j + 3][head];
            const __half *p0 = (const __half*)&k0, *p1 = (const __half*)&k1;
            const __half *p2 = (const __half*)&k2, *p3 = (const __half*)&k3;
#pragma unroll
            for (int k = 0; k < 8; ++k) acc[k] += w0 * __half2float(p0[k]);
#pragma unroll
            for (int k = 0; k < 8; ++k) acc[k] += w1 * __half2float(p1[k]);
#pragma unroll
            for (int k = 0; k < 8; ++k) acc[k] += w2 * __half2float(p2[k]);
#pragma unroll
            for (int k = 0; k < 8; ++k) acc[k] += w3 * __half2float(p3[k]);
        }
        for (; j < tot; ++j) {
            uint4 pk = hp[(size_t)ss[j] * 64 + lane];
            float wj = ws[j][head];
            const __half* p = (const __half*)&pk;
#pragma unroll
            for (int k = 0; k < 8; ++k) acc[k] += wj * __half2float(p[k]);
        }
    } else {
        // unreachable in practice (max degree < 64); deterministic since csrsrc sorted
        float4 m4 = make_float4(-1e30f, -1e30f, -1e30f, -1e30f);
        for (int base = 0; base < tot; base += 64) {
            int j = base + lane;
            float4 l4 = make_float4(-1e30f, -1e30f, -1e30f, -1e30f);
            if (j < tot) {
                int s = (j < deg) ? csrsrc[r0 + j] : node;
                float4 a = als4[s];
                l4.x = lrelu(a.x + aldn.x); l4.y = lrelu(a.y + aldn.y);
                l4.z = lrelu(a.z + aldn.z); l4.w = lrelu(a.w + aldn.w);
            }
#pragma unroll
            for (int off = 32; off > 0; off >>= 1) {
                l4.x = fmaxf(l4.x, __shfl_xor(l4.x, off));
                l4.y = fmaxf(l4.y, __shfl_xor(l4.y, off));
                l4.z = fmaxf(l4.z, __shfl_xor(l4.z, off));
                l4.w = fmaxf(l4.w, __shfl_xor(l4.w, off));
            }
            m4.x = fmaxf(m4.x, l4.x); m4.y = fmaxf(m4.y, l4.y);
            m4.z = fmaxf(m4.z, l4.z); m4.w = fmaxf(m4.w, l4.w);
        }
        d4 = make_float4(0.f, 0.f, 0.f, 0.f);
        for (int base = 0; base < tot; base += 64) {
            int j = base + lane;
            int s = node;
            float4 w4 = make_float4(0.f, 0.f, 0.f, 0.f);
            if (j < tot) {
                if (j < deg) s = csrsrc[r0 + j];
                float4 a = als4[s];
                w4.x = expf(lrelu(a.x + aldn.x) - m4.x);
                w4.y = expf(lrelu(a.y + aldn.y) - m4.y);
                w4.z = expf(lrelu(a.z + aldn.z) - m4.z);
                w4.w = expf(lrelu(a.w + aldn.w) - m4.w);
            }
            float4 p4 = w4;
#pragma unroll
            for (int off = 32; off > 0; off >>= 1) {
                p4.x += __shfl_xor(p4.x, off);
                p4.y += __shfl_xor(p4.y, off);
                p4.z += __shfl_xor(p4.z, off);
                p4.w += __shfl_xor(p4.w, off);
            }
            d4.x += p4.x; d4.y += p4.y; d4.z += p4.z; d4.w += p4.w;
            int lim = min(64, tot - base);
            for (int j2 = 0; j2 < lim; ++j2) {
                int sj = __shfl(s, j2);
                float w0 = __shfl(w4.x, j2), w1 = __shfl(w4.y, j2);
                float w2 = __shfl(w4.z, j2), w3 = __shfl(w4.w, j2);
                float wj = (head < 2) ? (head == 0 ? w0 : w1) : (head == 2 ? w2 : w3);
                const uint4 pk = *((const uint4*)(h + (size_t)sj * 512) + lane);
                const __half* p = (const __half*)&pk;
#pragma unroll
                for (int k = 0; k < 8; ++k) acc[k] += wj * __half2float(p[k]);
            }
        }
    }

    const float dsel = (head < 2) ? (head == 0 ? d4.x : d4.y) : (head == 2 ? d4.z : d4.w);
    const float inv = 1.f / dsel;
    const float4 b0 = ((const float4*)bias)[lane * 2];
    const float4 b1 = ((const float4*)bias)[lane * 2 + 1];
    float v[8];
    v[0] = acc[0] * inv + b0.x; v[1] = acc[1] * inv + b0.y;
    v[2] = acc[2] * inv + b0.z; v[3] = acc[3] * inv + b0.w;
    v[4] = acc[4] * inv + b1.x; v[5] = acc[5] * inv + b1.y;
    v[6] = acc[6] * inv + b1.z; v[7] = acc[7] * inv + b1.w;
#pragma unroll
    for (int k = 0; k < 8; ++k) v[k] = (v[k] > 0.f) ? v[k] : expm1f(v[k]);
    float4* orow = (float4*)(x1 + (size_t)node * 512);
    orow[lane * 2]     = make_float4(v[0], v[1], v[2], v[3]);
    orow[lane * 2 + 1] = make_float4(v[4], v[5], v[6], v[7]);
}

// ---------- layer-2 fused agg + relu + graph-max-pool: ONE NODE PER 64-THREAD BLOCK ----------
__global__ __launch_bounds__(64) void agg2_k(const __half* __restrict__ h,
                                             const float* __restrict__ als,
                                             const float* __restrict__ ald,
                                             const int* __restrict__ rowptr,
                                             const int* __restrict__ csrsrc,
                                             const float* __restrict__ bias,
                                             const int* __restrict__ batch,
                                             int* __restrict__ pooled) {
    __shared__ int   ss[64];
    __shared__ float ws[64];
    const int node = blockIdx.x;
    const int lane = threadIdx.x;
    const int r0 = rowptr[node];
    const int deg = rowptr[node + 1] - r0;
    const int tot = deg + 1;
    const float aldn = ald[node];

    float acc0 = 0.f, acc1 = 0.f;
    float denom;

    if (tot <= 64) {
        int s = node;
        if (lane < deg) s = csrsrc[r0 + lane];
        float l = -1e30f, w = 0.f;
        if (lane < tot) l = lrelu(als[s] + aldn);
        float m = l;
#pragma unroll
        for (int off = 32; off > 0; off >>= 1) m = fmaxf(m, __shfl_xor(m, off));
        if (lane < tot) w = expf(l - m);
        denom = w;
#pragma unroll
        for (int off = 32; off > 0; off >>= 1) denom += __shfl_xor(denom, off);
        ss[lane] = s;
        ws[lane] = w;
        const unsigned* hp = (const unsigned*)h;   // 64 half2 per row of 128 halfs
        int j = 0;
        for (; j + 8 <= tot; j += 8) {
            unsigned k0 = hp[(size_t)ss[j]     * 64 + lane];
            unsigned k1 = hp[(size_t)ss[j + 1] * 64 + lane];
            unsigned k2 = hp[(size_t)ss[j + 2] * 64 + lane];
            unsigned k3 = hp[(size_t)ss[j + 3] * 64 + lane];
            unsigned k4 = hp[(size_t)ss[j + 4] * 64 + lane];
            unsigned k5 = hp[(size_t)ss[j + 5] * 64 + lane];
            unsigned k6 = hp[(size_t)ss[j + 6] * 64 + lane];
            unsigned k7 = hp[(size_t)ss[j + 7] * 64 + lane];
            float w0 = ws[j], w1 = ws[j + 1], w2 = ws[j + 2], w3 = ws[j + 3];
            float w4 = ws[j + 4], w5 = ws[j + 5], w6 = ws[j + 6], w7 = ws[j + 7];
            float2 f0 = __half22float2(*(__half2*)&k0);
            float2 f1 = __half22float2(*(__half2*)&k1);
            float2 f2 = __half22float2(*(__half2*)&k2);
            float2 f3 = __half22float2(*(__half2*)&k3);
            float2 f4 = __half22float2(*(__half2*)&k4);
            float2 f5 = __half22float2(*(__half2*)&k5);
            float2 f6 = __half22float2(*(__half2*)&k6);
            float2 f7 = __half22float2(*(__half2*)&k7);
            acc0 += w0 * f0.x; acc1 += w0 * f0.y;
            acc0 += w1 * f1.x; acc1 += w1 * f1.y;
            acc0 += w2 * f2.x; acc1 += w2 * f2.y;
            acc0 += w3 * f3.x; acc1 += w3 * f3.y;
            acc0 += w4 * f4.x; acc1 += w4 * f4.y;
            acc0 += w5 * f5.x; acc1 += w5 * f5.y;
            acc0 += w6 * f6.x; acc1 += w6 * f6.y;
            acc0 += w7 * f7.x; acc1 += w7 * f7.y;
        }
        for (; j < tot; ++j) {
            unsigned pk = hp[(size_t)ss[j] * 64 + lane];
            float wj = ws[j];
            float2 f = __half22float2(*(__half2*)&pk);
            acc0 += wj * f.x;
            acc1 += wj * f.y;
        }
    } else {
        float m = -1e30f;
        for (int base = 0; base < tot; base += 64) {
            int j = base + lane;
            float l = -1e30f;
            if (j < tot) {
                int s = (j < deg) ? csrsrc[r0 + j] : node;
                l = lrelu(als[s] + aldn);
            }
#pragma unroll
            for (int off = 32; off > 0; off >>= 1) l = fmaxf(l, __shfl_xor(l, off));
            m = fmaxf(m, l);
        }
        denom = 0.f;
        for (int base = 0; base < tot; base += 64) {
            int j = base + lane;
            int s = node;
            float w = 0.f;
            if (j < tot) {
                if (j < deg) s = csrsrc[r0 + j];
                w = expf(lrelu(als[s] + aldn) - m);
            }
            float ws2 = w;
#pragma unroll
            for (int off = 32; off > 0; off >>= 1) ws2 += __shfl_xor(ws2, off);
            denom += ws2;
            int lim = min(64, tot - base);
            for (int j2 = 0; j2 < lim; ++j2) {
                int sj = __shfl(s, j2);
                float wj = __shfl(w, j2);
                float2 f = __half22float2(((const __half2*)(h + (size_t)sj * 128))[lane]);
                acc0 += wj * f.x;
                acc1 += wj * f.y;
            }
        }
    }

    const float inv = 1.f / denom;
    float v0 = fmaxf(acc0 * inv + bias[lane * 2], 0.f);
    float v1 = fmaxf(acc1 * inv + bias[lane * 2 + 1], 0.f);
    int* pb = pooled + batch[node] * 128;
    atomicMax(&pb[lane * 2], __float_as_int(v0));
    atomicMax(&pb[lane * 2 + 1], __float_as_int(v1));
}

// ---------- final MLP head: one block per graph ----------
__global__ __launch_bounds__(64) void fc_k(const float* __restrict__ pooled,
                                           const float* __restrict__ w1,
                                           const float* __restrict__ b1,
                                           const float* __restrict__ w2,
                                           const float* __restrict__ b2,
                                           float* __restrict__ out) {
    int g = blockIdx.x;
    __shared__ float p[128];
    int t = threadIdx.x;
    p[t] = pooled[g * 128 + t];
    p[t + 64] = pooled[g * 128 + 64 + t];
    __syncthreads();
    float acc = 0.f;
    if (t < 16) {
        float s = b1[t];
        for (int c = 0; c < 128; ++c) s += p[c] * w1[c * 16 + t];
        s = fmaxf(s, 0.f);
        acc = s * w2[t];
    }
#pragma unroll
    for (int off = 8; off > 0; off >>= 1) acc += __shfl_down(acc, off);
    if (t == 0) out[g] = acc + b2[0];
}

extern "C" void kernel_launch(void* const* d_in, const int* in_sizes, int n_in,
                              void* d_out, int out_size, void* d_ws, size_t ws_size,
                              hipStream_t stream) {
    const float* x      = (const float*)d_in[0];
    const int*   ei     = (const int*)d_in[1];
    const int*   batch  = (const int*)d_in[2];
    const float* W1     = (const float*)d_in[3];
    const float* a_src1 = (const float*)d_in[4];
    const float* a_dst1 = (const float*)d_in[5];
    const float* b1     = (const float*)d_in[6];
    const float* W2     = (const float*)d_in[7];
    const float* a_src2 = (const float*)d_in[8];
    const float* a_dst2 = (const float*)d_in[9];
    const float* b2     = (const float*)d_in[10];
    const float* fc1w   = (const float*)d_in[11];
    const float* fc1b   = (const float*)d_in[12];
    const float* fc2w   = (const float*)d_in[13];
    const float* fc2b   = (const float*)d_in[14];
    float* out = (float*)d_out;

    const int* src = ei;
    const int* dst = ei + E_EDGES;

    // ---- workspace layout (4-byte units) ----
    int*   cnt    = (int*)d_ws;                     // 20,000 (zero region start)
    int*   cur    = cnt + 20000;                    // 20,000
    int*   pooled = cur + 20000;                    // 32,768
    // zero region = 72,768 * 4 = 291,072 bytes
    int*   rowptr = pooled + 32768;                 // 20,004
    int*   part   = rowptr + 20004;                 // 128
    int*   csrsrc = part + 128;                     // 320,000
    __half* h1h   = (__half*)(csrsrc + 320000);     // 10,240,000 halfs
    __half* h2h   = h1h + 10240000;                 //  2,560,000 halfs
    float* als1   = (float*)(h2h + 2560000);        //     80,000
    float* ald1   = als1 + 80000;                   //     80,000
    float* als2   = ald1 + 80000;                   //     20,000
    float* ald2   = als2 + 20000;                   //     20,000
    __half* w1t   = (__half*)(ald2 + 20000);        //     65,536 halfs
    __half* w2t   = w1t + 65536;                    //     65,536 halfs
    float* x1     = (float*)(w2t + 65536);          // 10,240,000 floats

    (void)hipMemsetAsync(d_ws, 0, 72768 * 4, stream);

    // ---- CSR build (+ fused weight prep) + canonical sort ----
    cntprep_k<<<(E_EDGES + 255) / 256, 256, 0, stream>>>(dst, cnt, W1, w1t, W2, w2t);
    scan1_k<<<SCAN_B, 256, 0, stream>>>(cnt, part);
    scan2_k<<<1, 128, 0, stream>>>(part);
    scan3_k<<<SCAN_B, 256, 0, stream>>>(cnt, part, rowptr);
    scat_k<<<(E_EDGES + 255) / 256, 256, 0, stream>>>(src, dst, rowptr, cur, csrsrc);
    sortb_k<<<N_NODES / 4, 256, 0, stream>>>(rowptr, csrsrc);

    // ---- layer 1: h1 = x @ W1 + fused attention dots ----
    fgemm_k<__half><<<dim3(313, 4), 256, 0, stream>>>(x, w1t, N_NODES, 512, 128, h1h,
                                                      als1, ald1, a_src1, a_dst1);

    agg1_k<<<N_NODES, 64, 0, stream>>>(h1h, (const float4*)als1, (const float4*)ald1,
                                       rowptr, csrsrc, b1, x1);

    // ---- layer 2: h2 = x1 @ W2 + fused attention dots ----
    fgemm_k<__half><<<dim3(313, 1), 256, 0, stream>>>(x1, w2t, N_NODES, 128, 512, h2h,
                                                      als2, ald2, a_src2, a_dst2);

    agg2_k<<<N_NODES, 64, 0, stream>>>(h2h, als2, ald2, rowptr, csrsrc, b2,
                                       batch, pooled);

    // ---- head ----
    fc_k<<<G_GRAPHS, 64, 0, stream>>>((const float*)pooled, fc1w, fc1b, fc2w, fc2b, out);
}